// Round 7
// baseline (305.203 us; speedup 1.0000x reference)
//
#include <hip/hip_runtime.h>

// Problem constants (reference shape (64,1,480,640) fp32)
#define B_SAMPLES 64
#define F4PS      76800      // float4 per sample
#define BPS       30         // blocks per sample
#define NBLK      (B_SAMPLES * BPS)   // 1920
#define F4PB      2560       // float4 per block
#define TPB       256        // threads per block
#define ITERS     10         // F4PB / TPB
#define WPB       4          // waves per block
#define EPS_DET   1e-6f
#define BM_DW     320        // bitmask dwords per block (1280 B = 10240 bits)

typedef __attribute__((address_space(3))) void       lds_void;
typedef const __attribute__((address_space(1))) void gbl_void;

__device__ __forceinline__ bool finitef(float x) {
    return (__float_as_uint(x) & 0x7f800000u) != 0x7f800000u;
}

// ---------------------------------------------------------------------------
// Local mask-layout detection: block scans 4 KiB of ITS OWN mask chunk.
// int32 0/1 => bytes at 4k+{1,2,3} all zero; byte-bool => ~50% of ~3072
// scanned high-bytes nonzero (P[miss] ~ 2^-3072).
// ---------------------------------------------------------------------------
__device__ __forceinline__ bool detect_byte_layout(const void* mask, int base4,
                                                   int* sflag) {
    const uint4* m16 =
        (const uint4*)((const unsigned char*)mask + (size_t)base4 * 4);
    uint4 m = m16[threadIdx.x];                     // 256 thr x 16 B = 4 KiB
    unsigned v = (m.x | m.y | m.z | m.w) & 0xffffff00u;
    if (threadIdx.x == 0) *sflag = 0;
    __syncthreads();
    if (__any(v != 0) && (threadIdx.x & 63) == 0) *sflag = 1;
    __syncthreads();
    return *sflag != 0;
}

// async stage: p 1KB + t 1KB (+ mask 256B) per wave-tile -> LDS
__device__ __forceinline__ void stage3(const float4* gp, const float4* gt,
                                       const unsigned* gm, unsigned char* lbuf) {
    __builtin_amdgcn_global_load_lds((gbl_void*)gp, (lds_void*)lbuf, 16, 0, 0);
    __builtin_amdgcn_global_load_lds((gbl_void*)gt, (lds_void*)(lbuf + 1024), 16, 0, 0);
    __builtin_amdgcn_global_load_lds((gbl_void*)gm, (lds_void*)(lbuf + 2048), 4, 0, 0);
}
__device__ __forceinline__ void stage2(const float4* gp, const float4* gt,
                                       unsigned char* lbuf) {
    __builtin_amdgcn_global_load_lds((gbl_void*)gp, (lds_void*)lbuf, 16, 0, 0);
    __builtin_amdgcn_global_load_lds((gbl_void*)gt, (lds_void*)(lbuf + 1024), 16, 0, 0);
}

// ---------------------------------------------------------------------------
// Kernel 1: masked partial sums {n, sum_p, sum_t, sum_p2, sum_pt}; if BITPK,
// also emit packed validity bits (1 bit/element) for pass 2.
// ---------------------------------------------------------------------------
template <bool BITPK>
__global__ void
sums_kernel(const float* __restrict__ pred, const float* __restrict__ target,
            const void* __restrict__ mask, float* __restrict__ partials,
            unsigned* __restrict__ bitpack, int* __restrict__ ticket) {
    const int s   = blockIdx.x / BPS;
    const int sub = blockIdx.x % BPS;
    const int base4 = s * F4PS + sub * F4PB;
    const int tid = threadIdx.x, lane = tid & 63, w = tid >> 6;

    if (BITPK && blockIdx.x == 0 && tid == 0) *ticket = 0;  // reset for resid

    __shared__ __align__(16) unsigned char stg[WPB][2][2304];
    __shared__ unsigned long long bm64[WPB * ITERS * 4];    // 1280 B
    __shared__ float red[WPB][5];
    __shared__ int sflag;

    const bool byteLayout = detect_byte_layout(mask, base4, &sflag);

    const float4* p4 = (const float4*)pred;
    const float4* t4 = (const float4*)target;

    float n = 0.f, sp = 0.f, st = 0.f, sp2 = 0.f, spt = 0.f;
    auto acc1 = [&](float p, float t, bool ok) {
        float pv = ok ? p : 0.f;
        float tv = ok ? t : 0.f;
        n   += ok ? 1.f : 0.f;
        sp  += pv;  st += tv;  sp2 += pv * pv;  spt += pv * tv;
    };

    if (byteLayout) {
        const unsigned* m4 = (const unsigned*)mask;
        unsigned char* buf0 = &stg[w][0][0];
        unsigned char* buf1 = &stg[w][1][0];
        const int i0 = base4 + w * 64 + lane;
        stage3(p4 + i0, t4 + i0, m4 + i0, buf0);
#pragma unroll
        for (int t = 0; t < ITERS; ++t) {
            unsigned char* cur = (t & 1) ? buf1 : buf0;
            unsigned char* nxt = (t & 1) ? buf0 : buf1;
            if (t < ITERS - 1) {
                const int i4 = i0 + (t + 1) * TPB;
                stage3(p4 + i4, t4 + i4, m4 + i4, nxt);
                __builtin_amdgcn_sched_barrier(0);
                asm volatile("s_waitcnt vmcnt(3)" ::: "memory");
            } else {
                __builtin_amdgcn_sched_barrier(0);
                asm volatile("s_waitcnt vmcnt(0)" ::: "memory");
            }
            __builtin_amdgcn_sched_barrier(0);
            const float4  pv = *(const float4*)(cur + (size_t)lane * 16);
            const float4  tv = *(const float4*)(cur + 1024 + (size_t)lane * 16);
            const unsigned mm = *(const unsigned*)(cur + 2048 + (size_t)lane * 4);
            bool o0 = (mm & 0x000000ffu) && finitef(pv.x) && finitef(tv.x);
            bool o1 = (mm & 0x0000ff00u) && finitef(pv.y) && finitef(tv.y);
            bool o2 = (mm & 0x00ff0000u) && finitef(pv.z) && finitef(tv.z);
            bool o3 = (mm & 0xff000000u) && finitef(pv.w) && finitef(tv.w);
            if (BITPK) {
                unsigned long long B0 = __ballot(o0), B1 = __ballot(o1);
                unsigned long long B2 = __ballot(o2), B3 = __ballot(o3);
                if (lane == 0) {
                    const int c = (w * ITERS + t) * 4;
                    bm64[c] = B0; bm64[c + 1] = B1;
                    bm64[c + 2] = B2; bm64[c + 3] = B3;
                }
            }
            acc1(pv.x, tv.x, o0); acc1(pv.y, tv.y, o1);
            acc1(pv.z, tv.z, o2); acc1(pv.w, tv.w, o3);
        }
    } else {
        const int4* m4 = (const int4*)mask;
        for (int t = 0; t < ITERS; ++t) {
            const int i4 = base4 + t * TPB + tid;  // NB: per-thread layout
            float4 p = p4[i4]; float4 tt = t4[i4]; int4 mm = m4[i4];
            bool o0 = mm.x && finitef(p.x) && finitef(tt.x);
            bool o1 = mm.y && finitef(p.y) && finitef(tt.y);
            bool o2 = mm.z && finitef(p.z) && finitef(tt.z);
            bool o3 = mm.w && finitef(p.w) && finitef(tt.w);
            if (BITPK) {
                // per-thread layout: thread tid <-> (wave w, lane) same mapping
                unsigned long long B0 = __ballot(o0), B1 = __ballot(o1);
                unsigned long long B2 = __ballot(o2), B3 = __ballot(o3);
                if (lane == 0) {
                    const int c = (w * ITERS + t) * 4;
                    bm64[c] = B0; bm64[c + 1] = B1;
                    bm64[c + 2] = B2; bm64[c + 3] = B3;
                }
            }
            acc1(p.x, tt.x, o0); acc1(p.y, tt.y, o1);
            acc1(p.z, tt.z, o2); acc1(p.w, tt.w, o3);
        }
    }

    // block reduce 5 quantities -> partials
    {
        float vals[5] = {n, sp, st, sp2, spt};
#pragma unroll
        for (int q = 0; q < 5; ++q) {
            float v = vals[q];
#pragma unroll
            for (int off = 32; off; off >>= 1) v += __shfl_xor(v, off);
            if (lane == 0) red[w][q] = v;
        }
        __syncthreads();   // also makes bm64 visible block-wide
        if (tid == 0) {
#pragma unroll
            for (int q = 0; q < 5; ++q)
                partials[(size_t)blockIdx.x * 5 + q] =
                    red[0][q] + red[1][q] + red[2][q] + red[3][q];
        }
    }
    if (BITPK) {
        const unsigned* bm32 = (const unsigned*)bm64;
        unsigned* g = bitpack + (size_t)blockIdx.x * BM_DW;
        g[tid] = bm32[tid];
        if (tid < BM_DW - TPB) g[TPB + tid] = bm32[TPB + tid];
    }
}

// ---------------------------------------------------------------------------
// Kernel 2: solve (a,b) (wave 0), residual pass, then last-block final.
// BITPK: validity from packed bits (no mask reads, no detect).
// ---------------------------------------------------------------------------
template <bool BITPK>
__global__ void
resid_kernel(const float* __restrict__ pred, const float* __restrict__ target,
             const void* __restrict__ mask, const float* __restrict__ partials,
             float* __restrict__ rpart, const unsigned* __restrict__ bitpack,
             int* __restrict__ ticket, float* __restrict__ out) {
    const int s   = blockIdx.x / BPS;
    const int sub = blockIdx.x % BPS;
    const int base4 = s * F4PS + sub * F4PB;
    const int tid = threadIdx.x, lane = tid & 63, w = tid >> 6;

    __shared__ __align__(16) unsigned char stg[WPB][2][2304];
    __shared__ unsigned long long bml64[WPB * ITERS * 4];   // 1280 B
    __shared__ float red[WPB];
    __shared__ float s_ab[2];
    __shared__ int sflag;
    __shared__ int s_last;

    bool byteLayout = true;
    if (!BITPK) byteLayout = detect_byte_layout(mask, base4, &sflag);
    if (BITPK) {
        unsigned* b32 = (unsigned*)bml64;
        b32[tid] = bitpack[(size_t)blockIdx.x * BM_DW + tid];
        if (tid < BM_DW - TPB)
            b32[TPB + tid] = bitpack[(size_t)blockIdx.x * BM_DW + TPB + tid];
    }

    // wave 0: gather sample's 30 partial rows, butterfly, lane 0 solves
    if (tid < 64) {
        float q0 = 0.f, q1 = 0.f, q2 = 0.f, q3 = 0.f, q4 = 0.f;
        if (tid < BPS) {
            const float* q = partials + (size_t)(s * BPS + tid) * 5;
            q0 = q[0]; q1 = q[1]; q2 = q[2]; q3 = q[3]; q4 = q[4];
        }
#pragma unroll
        for (int off = 32; off; off >>= 1) {
            q0 += __shfl_xor(q0, off); q1 += __shfl_xor(q1, off);
            q2 += __shfl_xor(q2, off); q3 += __shfl_xor(q3, off);
            q4 += __shfl_xor(q4, off);
        }
        if (tid == 0) {
            float det = q0 * q3 - q1 * q1;
            bool safe = fabsf(det) > EPS_DET;
            float a  = safe ? (q0 * q4 - q1 * q2) / det : 1.f;
            float bb = safe ? (q2 - a * q1) / fmaxf(q0, 1.f) : 0.f;
            s_ab[0] = a; s_ab[1] = bb;
        }
    }
    __syncthreads();   // drains all vmem (vmcnt=0) before manual pipeline
    const float av = s_ab[0];
    const float bv = s_ab[1];

    const float4* p4 = (const float4*)pred;
    const float4* t4 = (const float4*)target;

    float r = 0.f;
    auto racc = [&](float p, float t, bool ok) {
        r += ok ? fabsf(av * p + bv - t) : 0.f;
    };

    unsigned char* buf0 = &stg[w][0][0];
    unsigned char* buf1 = &stg[w][1][0];
    const int i0 = base4 + w * 64 + lane;

    if (BITPK) {
        stage2(p4 + i0, t4 + i0, buf0);
#pragma unroll
        for (int t = 0; t < ITERS; ++t) {
            unsigned char* cur = (t & 1) ? buf1 : buf0;
            unsigned char* nxt = (t & 1) ? buf0 : buf1;
            if (t < ITERS - 1) {
                const int i4 = i0 + (t + 1) * TPB;
                stage2(p4 + i4, t4 + i4, nxt);
                __builtin_amdgcn_sched_barrier(0);
                asm volatile("s_waitcnt vmcnt(2)" ::: "memory");
            } else {
                __builtin_amdgcn_sched_barrier(0);
                asm volatile("s_waitcnt vmcnt(0)" ::: "memory");
            }
            __builtin_amdgcn_sched_barrier(0);
            const float4 pv = *(const float4*)(cur + (size_t)lane * 16);
            const float4 tv = *(const float4*)(cur + 1024 + (size_t)lane * 16);
            const int c = (w * ITERS + t) * 4;
            const unsigned long long B0 = bml64[c],     B1 = bml64[c + 1];
            const unsigned long long B2 = bml64[c + 2], B3 = bml64[c + 3];
            racc(pv.x, tv.x, (B0 >> lane) & 1ull);
            racc(pv.y, tv.y, (B1 >> lane) & 1ull);
            racc(pv.z, tv.z, (B2 >> lane) & 1ull);
            racc(pv.w, tv.w, (B3 >> lane) & 1ull);
        }
    } else if (byteLayout) {
        const unsigned* m4 = (const unsigned*)mask;
        stage3(p4 + i0, t4 + i0, m4 + i0, buf0);
#pragma unroll
        for (int t = 0; t < ITERS; ++t) {
            unsigned char* cur = (t & 1) ? buf1 : buf0;
            unsigned char* nxt = (t & 1) ? buf0 : buf1;
            if (t < ITERS - 1) {
                const int i4 = i0 + (t + 1) * TPB;
                stage3(p4 + i4, t4 + i4, m4 + i4, nxt);
                __builtin_amdgcn_sched_barrier(0);
                asm volatile("s_waitcnt vmcnt(3)" ::: "memory");
            } else {
                __builtin_amdgcn_sched_barrier(0);
                asm volatile("s_waitcnt vmcnt(0)" ::: "memory");
            }
            __builtin_amdgcn_sched_barrier(0);
            const float4  pv = *(const float4*)(cur + (size_t)lane * 16);
            const float4  tv = *(const float4*)(cur + 1024 + (size_t)lane * 16);
            const unsigned mm = *(const unsigned*)(cur + 2048 + (size_t)lane * 4);
            racc(pv.x, tv.x, (mm & 0x000000ffu) && finitef(pv.x) && finitef(tv.x));
            racc(pv.y, tv.y, (mm & 0x0000ff00u) && finitef(pv.y) && finitef(tv.y));
            racc(pv.z, tv.z, (mm & 0x00ff0000u) && finitef(pv.z) && finitef(tv.z));
            racc(pv.w, tv.w, (mm & 0xff000000u) && finitef(pv.w) && finitef(tv.w));
        }
    } else {
        const int4* m4 = (const int4*)mask;
        for (int t = 0; t < ITERS; ++t) {
            const int i4 = base4 + t * TPB + tid;
            float4 p = p4[i4]; float4 tt = t4[i4]; int4 mm = m4[i4];
            racc(p.x, tt.x, mm.x && finitef(p.x) && finitef(tt.x));
            racc(p.y, tt.y, mm.y && finitef(p.y) && finitef(tt.y));
            racc(p.z, tt.z, mm.z && finitef(p.z) && finitef(tt.z));
            racc(p.w, tt.w, mm.w && finitef(p.w) && finitef(tt.w));
        }
    }

    // block reduce -> rpart
    {
        float v = r;
#pragma unroll
        for (int off = 32; off; off >>= 1) v += __shfl_xor(v, off);
        if (lane == 0) red[w] = v;
        __syncthreads();
        if (tid == 0)
            rpart[blockIdx.x] = red[0] + red[1] + red[2] + red[3];
    }

    // last-block deterministic final reduction
    __threadfence();
    if (tid == 0) {
        int old = atomicAdd(ticket, 1);
        s_last = (old == NBLK - 1);
    }
    __syncthreads();
    if (s_last) {
        __threadfence();
        float* fr = (float*)&stg[0][0][0];   // reuse dead staging LDS
        float* fn = fr + NBLK;
        for (int i = tid; i < NBLK; i += TPB) {
            fr[i] = rpart[i];
            fn[i] = partials[(size_t)i * 5];
        }
        __syncthreads();
        if (tid < 64) {
            const int ss = tid;
            double rr = 0.0, nn = 0.0;
            for (int b = 0; b < BPS; ++b) {
                rr += (double)fr[ss * BPS + b];
                nn += (double)fn[ss * BPS + b];
            }
            double per = rr / fmax(nn, 1.0);
            double inc = (nn >= 2.0) ? 1.0 : 0.0;
            double v = per * inc;
#pragma unroll
            for (int off = 32; off; off >>= 1) {
                v   += __shfl_down(v, off);
                inc += __shfl_down(inc, off);
            }
            if (ss == 0) out[0] = (float)(inc > 0.0 ? v / fmax(inc, 1.0) : 0.0);
        }
    }
}

extern "C" void kernel_launch(void* const* d_in, const int* in_sizes, int n_in,
                              void* d_out, int out_size, void* d_ws, size_t ws_size,
                              hipStream_t stream) {
    const float* pred = (const float*)d_in[0];
    const float* target = (const float*)d_in[1];
    const void* mask = d_in[2];
    float* out = (float*)d_out;

    // workspace layout
    int* ticket = (int*)d_ws;                               // [0, 64)
    float* partials = (float*)((char*)d_ws + 64);           // 1920*5 fp32
    float* rpart = partials + (size_t)NBLK * 5;             // 1920 fp32
    unsigned* bitpack = (unsigned*)(rpart + NBLK);          // 1920*320 u32

    const size_t need = 64 + (size_t)NBLK * 5 * 4 + (size_t)NBLK * 4 +
                        (size_t)NBLK * BM_DW * 4;
    const bool bitpk = ws_size >= need;

    if (bitpk) {
        sums_kernel<true><<<NBLK, TPB, 0, stream>>>(pred, target, mask,
                                                    partials, bitpack, ticket);
        resid_kernel<true><<<NBLK, TPB, 0, stream>>>(pred, target, mask,
                                                     partials, rpart, bitpack,
                                                     ticket, out);
    } else {
        sums_kernel<false><<<NBLK, TPB, 0, stream>>>(pred, target, mask,
                                                     partials, bitpack, ticket);
        // still need a ticket reset for the non-bitpack path: sums<false>
        // doesn't write it, so do it with a tiny async memset (4 bytes).
        hipMemsetAsync(ticket, 0, 4, stream);
        resid_kernel<false><<<NBLK, TPB, 0, stream>>>(pred, target, mask,
                                                      partials, rpart, bitpack,
                                                      ticket, out);
    }
}

// Round 8
// 82.881 us; speedup vs baseline: 3.6824x; 3.6824x over previous
//
#include <hip/hip_runtime.h>
#include <hip/hip_cooperative_groups.h>

namespace cg = cooperative_groups;

// Problem constants (reference shape (64,1,480,640) fp32)
#define B_SAMPLES 64
#define F4PS      76800      // float4 per sample
#define BPS       30         // blocks per sample
#define NBLK      (B_SAMPLES * BPS)   // 1920
#define F4PB      2560       // float4 per block
#define TPB       256        // threads per block
#define ITERS     10         // F4PB / TPB
#define WPB       4          // waves per block
#define EPS_DET   1e-6f

typedef __attribute__((address_space(3))) void       lds_void;
typedef const __attribute__((address_space(1))) void gbl_void;

__device__ __forceinline__ bool finitef(float x) {
    return (__float_as_uint(x) & 0x7f800000u) != 0x7f800000u;
}

// Local mask-layout detection: block scans 4 KiB of ITS OWN mask chunk.
// int32 0/1 => bytes at 4k+{1,2,3} all zero; byte-bool => ~50% of ~3072
// scanned high-bytes nonzero (P[miss] ~ 2^-3072).
__device__ __forceinline__ bool detect_byte_layout(const void* mask, int base4,
                                                   int* sflag) {
    const uint4* m16 =
        (const uint4*)((const unsigned char*)mask + (size_t)base4 * 4);
    uint4 m = m16[threadIdx.x];                     // 256 thr x 16 B = 4 KiB
    unsigned v = (m.x | m.y | m.z | m.w) & 0xffffff00u;
    if (threadIdx.x == 0) *sflag = 0;
    __syncthreads();
    if (__any(v != 0) && (threadIdx.x & 63) == 0) *sflag = 1;
    __syncthreads();
    return *sflag != 0;
}

// async stage: p 1KB + t 1KB + mask 256B per wave-tile -> LDS
__device__ __forceinline__ void stage3(const float4* gp, const float4* gt,
                                       const unsigned* gm, unsigned char* lbuf) {
    __builtin_amdgcn_global_load_lds((gbl_void*)gp, (lds_void*)lbuf, 16, 0, 0);
    __builtin_amdgcn_global_load_lds((gbl_void*)gt, (lds_void*)(lbuf + 1024), 16, 0, 0);
    __builtin_amdgcn_global_load_lds((gbl_void*)gm, (lds_void*)(lbuf + 2048), 4, 0, 0);
}

// ===========================================================================
// Cooperative fused kernel: pass1 (sums) -> grid.sync -> solve -> pass2
// (residual). Loop bodies identical to the proven split kernels. Final
// reduction deliberately NOT embedded (kept as tiny separate kernel).
// ===========================================================================
__global__ void
fused(const float* __restrict__ pred, const float* __restrict__ target,
      const void* __restrict__ mask, float* __restrict__ partials,
      float* __restrict__ rpart) {
    const int s   = blockIdx.x / BPS;
    const int sub = blockIdx.x % BPS;
    const int base4 = s * F4PS + sub * F4PB;
    const int tid = threadIdx.x, lane = tid & 63, w = tid >> 6;

    __shared__ __align__(16) unsigned char stg[WPB][2][2304];
    __shared__ float red[WPB][5];
    __shared__ float s_ab[2];
    __shared__ int sflag;

    const bool byteLayout = detect_byte_layout(mask, base4, &sflag);

    const float4* p4 = (const float4*)pred;
    const float4* t4 = (const float4*)target;
    const unsigned* m4b = (const unsigned*)mask;

    unsigned char* buf0 = &stg[w][0][0];     // wave-uniform
    unsigned char* buf1 = &stg[w][1][0];
    const int i0 = base4 + w * 64 + lane;

    // ---------------- pass 1: masked sums ----------------
    float n = 0.f, sp = 0.f, st = 0.f, sp2 = 0.f, spt = 0.f;
    auto acc1 = [&](float p, float t, bool ok) {
        float pv = ok ? p : 0.f;
        float tv = ok ? t : 0.f;
        n   += ok ? 1.f : 0.f;
        sp  += pv;  st += tv;  sp2 += pv * pv;  spt += pv * tv;
    };

    if (byteLayout) {
        stage3(p4 + i0, t4 + i0, m4b + i0, buf0);
#pragma unroll
        for (int t = 0; t < ITERS; ++t) {
            unsigned char* cur = (t & 1) ? buf1 : buf0;
            unsigned char* nxt = (t & 1) ? buf0 : buf1;
            if (t < ITERS - 1) {
                const int i4 = i0 + (t + 1) * TPB;
                stage3(p4 + i4, t4 + i4, m4b + i4, nxt);
                __builtin_amdgcn_sched_barrier(0);
                asm volatile("s_waitcnt vmcnt(3)" ::: "memory");
            } else {
                __builtin_amdgcn_sched_barrier(0);
                asm volatile("s_waitcnt vmcnt(0)" ::: "memory");
            }
            __builtin_amdgcn_sched_barrier(0);
            const float4  pv = *(const float4*)(cur + (size_t)lane * 16);
            const float4  tv = *(const float4*)(cur + 1024 + (size_t)lane * 16);
            const unsigned mm = *(const unsigned*)(cur + 2048 + (size_t)lane * 4);
            acc1(pv.x, tv.x, (mm & 0x000000ffu) && finitef(pv.x) && finitef(tv.x));
            acc1(pv.y, tv.y, (mm & 0x0000ff00u) && finitef(pv.y) && finitef(tv.y));
            acc1(pv.z, tv.z, (mm & 0x00ff0000u) && finitef(pv.z) && finitef(tv.z));
            acc1(pv.w, tv.w, (mm & 0xff000000u) && finitef(pv.w) && finitef(tv.w));
        }
    } else {
        const int4* m4 = (const int4*)mask;
        for (int t = 0; t < ITERS; ++t) {
            const int i4 = base4 + t * TPB + tid;
            float4 p = p4[i4]; float4 tt = t4[i4]; int4 mm = m4[i4];
            acc1(p.x, tt.x, mm.x && finitef(p.x) && finitef(tt.x));
            acc1(p.y, tt.y, mm.y && finitef(p.y) && finitef(tt.y));
            acc1(p.z, tt.z, mm.z && finitef(p.z) && finitef(tt.z));
            acc1(p.w, tt.w, mm.w && finitef(p.w) && finitef(tt.w));
        }
    }

    {
        float vals[5] = {n, sp, st, sp2, spt};
#pragma unroll
        for (int q = 0; q < 5; ++q) {
            float v = vals[q];
#pragma unroll
            for (int off = 32; off; off >>= 1) v += __shfl_xor(v, off);
            if (lane == 0) red[w][q] = v;
        }
        __syncthreads();
        if (tid == 0) {
#pragma unroll
            for (int q = 0; q < 5; ++q)
                partials[(size_t)blockIdx.x * 5 + q] =
                    red[0][q] + red[1][q] + red[2][q] + red[3][q];
        }
    }

    // ---------------- grid barrier ----------------
    __threadfence();
    cg::this_grid().sync();
    __threadfence();

    // ---------------- solve (a,b); overlap pass-2 prologue stage ----------
    if (byteLayout)
        stage3(p4 + i0, t4 + i0, m4b + i0, buf0);   // prefetch tile 0 early

    if (tid < 64) {
        float q0 = 0.f, q1 = 0.f, q2 = 0.f, q3 = 0.f, q4 = 0.f;
        if (tid < BPS) {
            const float* q = partials + (size_t)(s * BPS + tid) * 5;
            q0 = q[0]; q1 = q[1]; q2 = q[2]; q3 = q[3]; q4 = q[4];
        }
#pragma unroll
        for (int off = 32; off; off >>= 1) {
            q0 += __shfl_xor(q0, off); q1 += __shfl_xor(q1, off);
            q2 += __shfl_xor(q2, off); q3 += __shfl_xor(q3, off);
            q4 += __shfl_xor(q4, off);
        }
        if (tid == 0) {
            float det = q0 * q3 - q1 * q1;
            bool safe = fabsf(det) > EPS_DET;
            float a  = safe ? (q0 * q4 - q1 * q2) / det : 1.f;
            float bb = safe ? (q2 - a * q1) / fmaxf(q0, 1.f) : 0.f;
            s_ab[0] = a; s_ab[1] = bb;
        }
    }
    __syncthreads();   // drains prologue vmem too (benign)
    const float av = s_ab[0];
    const float bv = s_ab[1];

    // ---------------- pass 2: residual ----------------
    float r = 0.f;
    auto racc = [&](float p, float t, bool ok) {
        r += ok ? fabsf(av * p + bv - t) : 0.f;
    };

    if (byteLayout) {
#pragma unroll
        for (int t = 0; t < ITERS; ++t) {
            unsigned char* cur = (t & 1) ? buf1 : buf0;
            unsigned char* nxt = (t & 1) ? buf0 : buf1;
            if (t < ITERS - 1) {
                const int i4 = i0 + (t + 1) * TPB;
                stage3(p4 + i4, t4 + i4, m4b + i4, nxt);
                __builtin_amdgcn_sched_barrier(0);
                asm volatile("s_waitcnt vmcnt(3)" ::: "memory");
            } else {
                __builtin_amdgcn_sched_barrier(0);
                asm volatile("s_waitcnt vmcnt(0)" ::: "memory");
            }
            __builtin_amdgcn_sched_barrier(0);
            const float4  pv = *(const float4*)(cur + (size_t)lane * 16);
            const float4  tv = *(const float4*)(cur + 1024 + (size_t)lane * 16);
            const unsigned mm = *(const unsigned*)(cur + 2048 + (size_t)lane * 4);
            racc(pv.x, tv.x, (mm & 0x000000ffu) && finitef(pv.x) && finitef(tv.x));
            racc(pv.y, tv.y, (mm & 0x0000ff00u) && finitef(pv.y) && finitef(tv.y));
            racc(pv.z, tv.z, (mm & 0x00ff0000u) && finitef(pv.z) && finitef(tv.z));
            racc(pv.w, tv.w, (mm & 0xff000000u) && finitef(pv.w) && finitef(tv.w));
        }
    } else {
        const int4* m4 = (const int4*)mask;
        for (int t = 0; t < ITERS; ++t) {
            const int i4 = base4 + t * TPB + tid;
            float4 p = p4[i4]; float4 tt = t4[i4]; int4 mm = m4[i4];
            racc(p.x, tt.x, mm.x && finitef(p.x) && finitef(tt.x));
            racc(p.y, tt.y, mm.y && finitef(p.y) && finitef(tt.y));
            racc(p.z, tt.z, mm.z && finitef(p.z) && finitef(tt.z));
            racc(p.w, tt.w, mm.w && finitef(p.w) && finitef(tt.w));
        }
    }

    {
        float v = r;
#pragma unroll
        for (int off = 32; off; off >>= 1) v += __shfl_xor(v, off);
        if (lane == 0) red[w][0] = v;
        __syncthreads();
        if (tid == 0)
            rpart[blockIdx.x] = red[0][0] + red[1][0] + red[2][0] + red[3][0];
    }
}

// ===========================================================================
// Fallback split kernels (proven R6 path)
// ===========================================================================
__global__ void
sums_kernel(const float* __restrict__ pred, const float* __restrict__ target,
            const void* __restrict__ mask, float* __restrict__ partials) {
    const int s   = blockIdx.x / BPS;
    const int sub = blockIdx.x % BPS;
    const int base4 = s * F4PS + sub * F4PB;
    const int tid = threadIdx.x, lane = tid & 63, w = tid >> 6;

    __shared__ __align__(16) unsigned char stg[WPB][2][2304];
    __shared__ float red[WPB][5];
    __shared__ int sflag;

    const bool byteLayout = detect_byte_layout(mask, base4, &sflag);
    const float4* p4 = (const float4*)pred;
    const float4* t4 = (const float4*)target;

    float n = 0.f, sp = 0.f, st = 0.f, sp2 = 0.f, spt = 0.f;
    auto acc1 = [&](float p, float t, bool ok) {
        float pv = ok ? p : 0.f;
        float tv = ok ? t : 0.f;
        n += ok ? 1.f : 0.f;
        sp += pv; st += tv; sp2 += pv * pv; spt += pv * tv;
    };

    if (byteLayout) {
        const unsigned* m4 = (const unsigned*)mask;
        unsigned char* buf0 = &stg[w][0][0];
        unsigned char* buf1 = &stg[w][1][0];
        const int i0 = base4 + w * 64 + lane;
        stage3(p4 + i0, t4 + i0, m4 + i0, buf0);
#pragma unroll
        for (int t = 0; t < ITERS; ++t) {
            unsigned char* cur = (t & 1) ? buf1 : buf0;
            unsigned char* nxt = (t & 1) ? buf0 : buf1;
            if (t < ITERS - 1) {
                const int i4 = i0 + (t + 1) * TPB;
                stage3(p4 + i4, t4 + i4, m4 + i4, nxt);
                __builtin_amdgcn_sched_barrier(0);
                asm volatile("s_waitcnt vmcnt(3)" ::: "memory");
            } else {
                __builtin_amdgcn_sched_barrier(0);
                asm volatile("s_waitcnt vmcnt(0)" ::: "memory");
            }
            __builtin_amdgcn_sched_barrier(0);
            const float4  pv = *(const float4*)(cur + (size_t)lane * 16);
            const float4  tv = *(const float4*)(cur + 1024 + (size_t)lane * 16);
            const unsigned mm = *(const unsigned*)(cur + 2048 + (size_t)lane * 4);
            acc1(pv.x, tv.x, (mm & 0x000000ffu) && finitef(pv.x) && finitef(tv.x));
            acc1(pv.y, tv.y, (mm & 0x0000ff00u) && finitef(pv.y) && finitef(tv.y));
            acc1(pv.z, tv.z, (mm & 0x00ff0000u) && finitef(pv.z) && finitef(tv.z));
            acc1(pv.w, tv.w, (mm & 0xff000000u) && finitef(pv.w) && finitef(tv.w));
        }
    } else {
        const int4* m4 = (const int4*)mask;
        for (int t = 0; t < ITERS; ++t) {
            const int i4 = base4 + t * TPB + tid;
            float4 p = p4[i4]; float4 tt = t4[i4]; int4 mm = m4[i4];
            acc1(p.x, tt.x, mm.x && finitef(p.x) && finitef(tt.x));
            acc1(p.y, tt.y, mm.y && finitef(p.y) && finitef(tt.y));
            acc1(p.z, tt.z, mm.z && finitef(p.z) && finitef(tt.z));
            acc1(p.w, tt.w, mm.w && finitef(p.w) && finitef(tt.w));
        }
    }

    {
        float vals[5] = {n, sp, st, sp2, spt};
#pragma unroll
        for (int q = 0; q < 5; ++q) {
            float v = vals[q];
#pragma unroll
            for (int off = 32; off; off >>= 1) v += __shfl_xor(v, off);
            if (lane == 0) red[w][q] = v;
        }
        __syncthreads();
        if (tid == 0) {
#pragma unroll
            for (int q = 0; q < 5; ++q)
                partials[(size_t)blockIdx.x * 5 + q] =
                    red[0][q] + red[1][q] + red[2][q] + red[3][q];
        }
    }
}

__global__ void
resid_kernel(const float* __restrict__ pred, const float* __restrict__ target,
             const void* __restrict__ mask, const float* __restrict__ partials,
             float* __restrict__ rpart) {
    const int s   = blockIdx.x / BPS;
    const int sub = blockIdx.x % BPS;
    const int base4 = s * F4PS + sub * F4PB;
    const int tid = threadIdx.x, lane = tid & 63, w = tid >> 6;

    __shared__ __align__(16) unsigned char stg[WPB][2][2304];
    __shared__ float red[WPB];
    __shared__ float s_ab[2];
    __shared__ int sflag;

    const bool byteLayout = detect_byte_layout(mask, base4, &sflag);
    const float4* p4 = (const float4*)pred;
    const float4* t4 = (const float4*)target;
    const unsigned* m4b = (const unsigned*)mask;

    unsigned char* buf0 = &stg[w][0][0];
    unsigned char* buf1 = &stg[w][1][0];
    const int i0 = base4 + w * 64 + lane;
    if (byteLayout)
        stage3(p4 + i0, t4 + i0, m4b + i0, buf0);

    if (tid < 64) {
        float q0 = 0.f, q1 = 0.f, q2 = 0.f, q3 = 0.f, q4 = 0.f;
        if (tid < BPS) {
            const float* q = partials + (size_t)(s * BPS + tid) * 5;
            q0 = q[0]; q1 = q[1]; q2 = q[2]; q3 = q[3]; q4 = q[4];
        }
#pragma unroll
        for (int off = 32; off; off >>= 1) {
            q0 += __shfl_xor(q0, off); q1 += __shfl_xor(q1, off);
            q2 += __shfl_xor(q2, off); q3 += __shfl_xor(q3, off);
            q4 += __shfl_xor(q4, off);
        }
        if (tid == 0) {
            float det = q0 * q3 - q1 * q1;
            bool safe = fabsf(det) > EPS_DET;
            float a  = safe ? (q0 * q4 - q1 * q2) / det : 1.f;
            float bb = safe ? (q2 - a * q1) / fmaxf(q0, 1.f) : 0.f;
            s_ab[0] = a; s_ab[1] = bb;
        }
    }
    __syncthreads();
    const float av = s_ab[0];
    const float bv = s_ab[1];

    float r = 0.f;
    auto racc = [&](float p, float t, bool ok) {
        r += ok ? fabsf(av * p + bv - t) : 0.f;
    };

    if (byteLayout) {
#pragma unroll
        for (int t = 0; t < ITERS; ++t) {
            unsigned char* cur = (t & 1) ? buf1 : buf0;
            unsigned char* nxt = (t & 1) ? buf0 : buf1;
            if (t < ITERS - 1) {
                const int i4 = i0 + (t + 1) * TPB;
                stage3(p4 + i4, t4 + i4, m4b + i4, nxt);
                __builtin_amdgcn_sched_barrier(0);
                asm volatile("s_waitcnt vmcnt(3)" ::: "memory");
            } else {
                __builtin_amdgcn_sched_barrier(0);
                asm volatile("s_waitcnt vmcnt(0)" ::: "memory");
            }
            __builtin_amdgcn_sched_barrier(0);
            const float4  pv = *(const float4*)(cur + (size_t)lane * 16);
            const float4  tv = *(const float4*)(cur + 1024 + (size_t)lane * 16);
            const unsigned mm = *(const unsigned*)(cur + 2048 + (size_t)lane * 4);
            racc(pv.x, tv.x, (mm & 0x000000ffu) && finitef(pv.x) && finitef(tv.x));
            racc(pv.y, tv.y, (mm & 0x0000ff00u) && finitef(pv.y) && finitef(tv.y));
            racc(pv.z, tv.z, (mm & 0x00ff0000u) && finitef(pv.z) && finitef(tv.z));
            racc(pv.w, tv.w, (mm & 0xff000000u) && finitef(pv.w) && finitef(tv.w));
        }
    } else {
        const int4* m4 = (const int4*)mask;
        for (int t = 0; t < ITERS; ++t) {
            const int i4 = base4 + t * TPB + tid;
            float4 p = p4[i4]; float4 tt = t4[i4]; int4 mm = m4[i4];
            racc(p.x, tt.x, mm.x && finitef(p.x) && finitef(tt.x));
            racc(p.y, tt.y, mm.y && finitef(p.y) && finitef(tt.y));
            racc(p.z, tt.z, mm.z && finitef(p.z) && finitef(tt.z));
            racc(p.w, tt.w, mm.w && finitef(p.w) && finitef(tt.w));
        }
    }

    {
        float v = r;
#pragma unroll
        for (int off = 32; off; off >>= 1) v += __shfl_xor(v, off);
        if (lane == 0) red[w] = v;
        __syncthreads();
        if (tid == 0)
            rpart[blockIdx.x] = red[0] + red[1] + red[2] + red[3];
    }
}

// Final loss. One wave, thread s = sample s.
__global__ void final_kernel(const float* __restrict__ partials,
                             const float* __restrict__ rpart,
                             float* __restrict__ out) {
    const int s = threadIdx.x;  // 64 threads = 1 wave
    double r = 0, n = 0;
    for (int b = 0; b < BPS; ++b) {
        r += (double)rpart[s * BPS + b];
        n += (double)partials[(size_t)(s * BPS + b) * 5 + 0];
    }
    double per = r / fmax(n, 1.0);
    double inc = (n >= 2.0) ? 1.0 : 0.0;
    double v = per * inc;
#pragma unroll
    for (int off = 32; off; off >>= 1) {
        v += __shfl_down(v, off);
        inc += __shfl_down(inc, off);
    }
    if (s == 0) out[0] = (float)(inc > 0.0 ? v / fmax(inc, 1.0) : 0.0);
}

extern "C" void kernel_launch(void* const* d_in, const int* in_sizes, int n_in,
                              void* d_out, int out_size, void* d_ws, size_t ws_size,
                              hipStream_t stream) {
    const float* pred = (const float*)d_in[0];
    const float* target = (const float*)d_in[1];
    const void* mask = d_in[2];
    float* out = (float*)d_out;

    float* partials = (float*)d_ws;                          // 1920*5 fp32
    float* rpart = partials + (size_t)NBLK * 5;              // 1920 fp32

    // Can all 1920 blocks be co-resident? (256 CUs on MI355X.) Pure host
    // query, no stream ops -> graph-capture safe. Deterministic per run.
    int perCU = 0;
    hipError_t qe =
        hipOccupancyMaxActiveBlocksPerMultiprocessor(&perCU, fused, TPB, 0);
    const bool coop = (qe == hipSuccess) && (perCU * 256 >= NBLK);

    if (coop) {
        void* args[] = {(void*)&pred, (void*)&target, (void*)&mask,
                        (void*)&partials, (void*)&rpart};
        hipLaunchCooperativeKernel((const void*)fused, dim3(NBLK), dim3(TPB),
                                   args, 0, stream);
    } else {
        sums_kernel<<<NBLK, TPB, 0, stream>>>(pred, target, mask, partials);
        resid_kernel<<<NBLK, TPB, 0, stream>>>(pred, target, mask, partials,
                                               rpart);
    }
    final_kernel<<<1, 64, 0, stream>>>(partials, rpart, out);
}

// Round 9
// 80.161 us; speedup vs baseline: 3.8074x; 1.0339x over previous
//
#include <hip/hip_runtime.h>

// Problem constants (reference shape (64,1,480,640) fp32)
#define B_SAMPLES 64
#define F4PS      76800      // float4 per sample
#define BPS       30         // blocks per sample
#define NBLK      (B_SAMPLES * BPS)   // 1920
#define TPB       256        // threads per block
#define ITERS     10         // tiles per block
#define TILE4     256        // float4 per block-tile (4 KB)
#define STEP4     (BPS * TILE4)   // per-iteration stride within sample (7680)
#define WPB       4          // waves per block
#define EPS_DET   1e-6f

typedef __attribute__((address_space(3))) void       lds_void;
typedef const __attribute__((address_space(1))) void gbl_void;

__device__ __forceinline__ bool finitef(float x) {
    return (__float_as_uint(x) & 0x7f800000u) != 0x7f800000u;
}

// Local mask-layout detection: block scans 4 KiB at its own first tile.
// int32 0/1 => bytes at 4k+{1,2,3} all zero; byte-bool => ~50% of ~3072
// scanned high-bytes nonzero (P[miss] ~ 2^-3072).
__device__ __forceinline__ bool detect_byte_layout(const void* mask, int base4,
                                                   int* sflag) {
    const uint4* m16 =
        (const uint4*)((const unsigned char*)mask + (size_t)base4 * 4);
    uint4 m = m16[threadIdx.x];                     // 256 thr x 16 B = 4 KiB
    unsigned v = (m.x | m.y | m.z | m.w) & 0xffffff00u;
    if (threadIdx.x == 0) *sflag = 0;
    __syncthreads();
    if (__any(v != 0) && (threadIdx.x & 63) == 0) *sflag = 1;
    __syncthreads();
    return *sflag != 0;
}

// async stage: p 1KB + t 1KB + mask 256B per wave-tile -> LDS
__device__ __forceinline__ void stage3(const float4* gp, const float4* gt,
                                       const unsigned* gm, unsigned char* lbuf) {
    __builtin_amdgcn_global_load_lds((gbl_void*)gp, (lds_void*)lbuf, 16, 0, 0);
    __builtin_amdgcn_global_load_lds((gbl_void*)gt, (lds_void*)(lbuf + 1024), 16, 0, 0);
    __builtin_amdgcn_global_load_lds((gbl_void*)gm, (lds_void*)(lbuf + 2048), 4, 0, 0);
}

// ---------------------------------------------------------------------------
// Kernel 1: per-block masked partial sums {n, sum_p, sum_t, sum_p2, sum_pt}.
// Sample-interleaved tiling: block (s,sub) iteration k reads tile k*BPS+sub
// of sample s, so all 30 blocks of a sample advance as one contiguous
// 120 KB front (compact device-wide address window, m13-style locality).
// ---------------------------------------------------------------------------
__global__ void
sums_kernel(const float* __restrict__ pred, const float* __restrict__ target,
            const void* __restrict__ mask, float* __restrict__ partials) {
    const int s   = blockIdx.x / BPS;
    const int sub = blockIdx.x % BPS;
    const int base4 = s * F4PS + sub * TILE4;        // first tile of block
    const int tid = threadIdx.x, lane = tid & 63, w = tid >> 6;

    __shared__ __align__(16) unsigned char stg[WPB][2][2304];
    __shared__ float red[WPB][5];
    __shared__ int sflag;

    const bool byteLayout = detect_byte_layout(mask, base4, &sflag);
    const float4* p4 = (const float4*)pred;
    const float4* t4 = (const float4*)target;

    float n = 0.f, sp = 0.f, st = 0.f, sp2 = 0.f, spt = 0.f;
    auto acc1 = [&](float p, float t, bool ok) {
        float pv = ok ? p : 0.f;
        float tv = ok ? t : 0.f;
        n += ok ? 1.f : 0.f;
        sp += pv; st += tv; sp2 += pv * pv; spt += pv * tv;
    };

    if (byteLayout) {
        const unsigned* m4 = (const unsigned*)mask;
        unsigned char* buf0 = &stg[w][0][0];
        unsigned char* buf1 = &stg[w][1][0];
        const int i0 = base4 + w * 64 + lane;
        stage3(p4 + i0, t4 + i0, m4 + i0, buf0);
#pragma unroll
        for (int t = 0; t < ITERS; ++t) {
            unsigned char* cur = (t & 1) ? buf1 : buf0;
            unsigned char* nxt = (t & 1) ? buf0 : buf1;
            if (t < ITERS - 1) {
                const int i4 = i0 + (t + 1) * STEP4;
                stage3(p4 + i4, t4 + i4, m4 + i4, nxt);
                __builtin_amdgcn_sched_barrier(0);
                asm volatile("s_waitcnt vmcnt(3)" ::: "memory");
            } else {
                __builtin_amdgcn_sched_barrier(0);
                asm volatile("s_waitcnt vmcnt(0)" ::: "memory");
            }
            __builtin_amdgcn_sched_barrier(0);
            const float4  pv = *(const float4*)(cur + (size_t)lane * 16);
            const float4  tv = *(const float4*)(cur + 1024 + (size_t)lane * 16);
            const unsigned mm = *(const unsigned*)(cur + 2048 + (size_t)lane * 4);
            acc1(pv.x, tv.x, (mm & 0x000000ffu) && finitef(pv.x) && finitef(tv.x));
            acc1(pv.y, tv.y, (mm & 0x0000ff00u) && finitef(pv.y) && finitef(tv.y));
            acc1(pv.z, tv.z, (mm & 0x00ff0000u) && finitef(pv.z) && finitef(tv.z));
            acc1(pv.w, tv.w, (mm & 0xff000000u) && finitef(pv.w) && finitef(tv.w));
        }
    } else {
        const int4* m4 = (const int4*)mask;
        for (int t = 0; t < ITERS; ++t) {
            const int i4 = base4 + t * STEP4 + tid;
            float4 p = p4[i4]; float4 tt = t4[i4]; int4 mm = m4[i4];
            acc1(p.x, tt.x, mm.x && finitef(p.x) && finitef(tt.x));
            acc1(p.y, tt.y, mm.y && finitef(p.y) && finitef(tt.y));
            acc1(p.z, tt.z, mm.z && finitef(p.z) && finitef(tt.z));
            acc1(p.w, tt.w, mm.w && finitef(p.w) && finitef(tt.w));
        }
    }

    {
        float vals[5] = {n, sp, st, sp2, spt};
#pragma unroll
        for (int q = 0; q < 5; ++q) {
            float v = vals[q];
#pragma unroll
            for (int off = 32; off; off >>= 1) v += __shfl_xor(v, off);
            if (lane == 0) red[w][q] = v;
        }
        __syncthreads();
        if (tid == 0) {
#pragma unroll
            for (int q = 0; q < 5; ++q)
                partials[(size_t)blockIdx.x * 5 + q] =
                    red[0][q] + red[1][q] + red[2][q] + red[3][q];
        }
    }
}

// ---------------------------------------------------------------------------
// Kernel 2: solve (a,b) from own sample's partials (wave 0), then residual
// pass with the same interleaved tiling + LDS pipeline.
// ---------------------------------------------------------------------------
__global__ void
resid_kernel(const float* __restrict__ pred, const float* __restrict__ target,
             const void* __restrict__ mask, const float* __restrict__ partials,
             float* __restrict__ rpart) {
    const int s   = blockIdx.x / BPS;
    const int sub = blockIdx.x % BPS;
    const int base4 = s * F4PS + sub * TILE4;
    const int tid = threadIdx.x, lane = tid & 63, w = tid >> 6;

    __shared__ __align__(16) unsigned char stg[WPB][2][2304];
    __shared__ float red[WPB];
    __shared__ float s_ab[2];
    __shared__ int sflag;

    const bool byteLayout = detect_byte_layout(mask, base4, &sflag);
    const float4* p4 = (const float4*)pred;
    const float4* t4 = (const float4*)target;
    const unsigned* m4b = (const unsigned*)mask;

    unsigned char* buf0 = &stg[w][0][0];
    unsigned char* buf1 = &stg[w][1][0];
    const int i0 = base4 + w * 64 + lane;
    if (byteLayout)
        stage3(p4 + i0, t4 + i0, m4b + i0, buf0);   // prefetch tile 0 early

    if (tid < 64) {
        float q0 = 0.f, q1 = 0.f, q2 = 0.f, q3 = 0.f, q4 = 0.f;
        if (tid < BPS) {
            const float* q = partials + (size_t)(s * BPS + tid) * 5;
            q0 = q[0]; q1 = q[1]; q2 = q[2]; q3 = q[3]; q4 = q[4];
        }
#pragma unroll
        for (int off = 32; off; off >>= 1) {
            q0 += __shfl_xor(q0, off); q1 += __shfl_xor(q1, off);
            q2 += __shfl_xor(q2, off); q3 += __shfl_xor(q3, off);
            q4 += __shfl_xor(q4, off);
        }
        if (tid == 0) {
            float det = q0 * q3 - q1 * q1;
            bool safe = fabsf(det) > EPS_DET;
            float a  = safe ? (q0 * q4 - q1 * q2) / det : 1.f;
            float bb = safe ? (q2 - a * q1) / fmaxf(q0, 1.f) : 0.f;
            s_ab[0] = a; s_ab[1] = bb;
        }
    }
    __syncthreads();
    const float av = s_ab[0];
    const float bv = s_ab[1];

    float r = 0.f;
    auto racc = [&](float p, float t, bool ok) {
        r += ok ? fabsf(av * p + bv - t) : 0.f;
    };

    if (byteLayout) {
#pragma unroll
        for (int t = 0; t < ITERS; ++t) {
            unsigned char* cur = (t & 1) ? buf1 : buf0;
            unsigned char* nxt = (t & 1) ? buf0 : buf1;
            if (t < ITERS - 1) {
                const int i4 = i0 + (t + 1) * STEP4;
                stage3(p4 + i4, t4 + i4, m4b + i4, nxt);
                __builtin_amdgcn_sched_barrier(0);
                asm volatile("s_waitcnt vmcnt(3)" ::: "memory");
            } else {
                __builtin_amdgcn_sched_barrier(0);
                asm volatile("s_waitcnt vmcnt(0)" ::: "memory");
            }
            __builtin_amdgcn_sched_barrier(0);
            const float4  pv = *(const float4*)(cur + (size_t)lane * 16);
            const float4  tv = *(const float4*)(cur + 1024 + (size_t)lane * 16);
            const unsigned mm = *(const unsigned*)(cur + 2048 + (size_t)lane * 4);
            racc(pv.x, tv.x, (mm & 0x000000ffu) && finitef(pv.x) && finitef(tv.x));
            racc(pv.y, tv.y, (mm & 0x0000ff00u) && finitef(pv.y) && finitef(tv.y));
            racc(pv.z, tv.z, (mm & 0x00ff0000u) && finitef(pv.z) && finitef(tv.z));
            racc(pv.w, tv.w, (mm & 0xff000000u) && finitef(pv.w) && finitef(tv.w));
        }
    } else {
        const int4* m4 = (const int4*)mask;
        for (int t = 0; t < ITERS; ++t) {
            const int i4 = base4 + t * STEP4 + tid;
            float4 p = p4[i4]; float4 tt = t4[i4]; int4 mm = m4[i4];
            racc(p.x, tt.x, mm.x && finitef(p.x) && finitef(tt.x));
            racc(p.y, tt.y, mm.y && finitef(p.y) && finitef(tt.y));
            racc(p.z, tt.z, mm.z && finitef(p.z) && finitef(tt.z));
            racc(p.w, tt.w, mm.w && finitef(p.w) && finitef(tt.w));
        }
    }

    {
        float v = r;
#pragma unroll
        for (int off = 32; off; off >>= 1) v += __shfl_xor(v, off);
        if (lane == 0) red[w] = v;
        __syncthreads();
        if (tid == 0)
            rpart[blockIdx.x] = red[0] + red[1] + red[2] + red[3];
    }
}

// Final loss. One wave, thread s = sample s.
__global__ void final_kernel(const float* __restrict__ partials,
                             const float* __restrict__ rpart,
                             float* __restrict__ out) {
    const int s = threadIdx.x;  // 64 threads = 1 wave
    double r = 0, n = 0;
    for (int b = 0; b < BPS; ++b) {
        r += (double)rpart[s * BPS + b];
        n += (double)partials[(size_t)(s * BPS + b) * 5 + 0];
    }
    double per = r / fmax(n, 1.0);
    double inc = (n >= 2.0) ? 1.0 : 0.0;
    double v = per * inc;
#pragma unroll
    for (int off = 32; off; off >>= 1) {
        v += __shfl_down(v, off);
        inc += __shfl_down(inc, off);
    }
    if (s == 0) out[0] = (float)(inc > 0.0 ? v / fmax(inc, 1.0) : 0.0);
}

extern "C" void kernel_launch(void* const* d_in, const int* in_sizes, int n_in,
                              void* d_out, int out_size, void* d_ws, size_t ws_size,
                              hipStream_t stream) {
    const float* pred = (const float*)d_in[0];
    const float* target = (const float*)d_in[1];
    const void* mask = d_in[2];
    float* out = (float*)d_out;

    float* partials = (float*)d_ws;                          // 1920*5 fp32
    float* rpart = partials + (size_t)NBLK * 5;              // 1920 fp32

    sums_kernel<<<NBLK, TPB, 0, stream>>>(pred, target, mask, partials);
    resid_kernel<<<NBLK, TPB, 0, stream>>>(pred, target, mask, partials,
                                           rpart);
    final_kernel<<<1, 64, 0, stream>>>(partials, rpart, out);
}